// Round 7
// baseline (1799.892 us; speedup 1.0000x reference)
//
#include <hip/hip_runtime.h>
#include <hip/hip_bf16.h>

#define NN 50000
#define NE 1600000
#define FIN 64
#define H 128
#define NL 5
#define NG 512
#define NC 10

typedef __attribute__((ext_vector_type(8))) short short8;
typedef __attribute__((ext_vector_type(4))) float f32x4;

// ws float-offset layout (total ~16.27M floats = 65 MB)
#define OFF_H     0
#define OFF_T     6400000
#define OFF_CUR   12800000   // 50016 ints (counts -> starts -> ends)
#define OFF_CSR   12850016   // 1.6M int2 (src, w_bits) = 3.2M words
#define OFF_POOL  16050016   // 65536 unsigned
#define OFF_FWF   16115552   // 245760 shorts (5 layers x 128x384 bf16 frag)
#define OFF_FWHH  16238432   // 49152 shorts

__device__ __forceinline__ short rne_bf16(float f){
    unsigned u = __float_as_uint(f);
    unsigned r = (u + 0x7FFFu + ((u >> 16) & 1u)) >> 16;
    return (short)r;
}

// ---------- CSR build ----------

__global__ void k_hist(const int* __restrict__ ei, int* __restrict__ cnt){
    int e = blockIdx.x*256 + threadIdx.x;
    if (e < NE) atomicAdd(&cnt[ei[NE + e]], 1);
}

__global__ void k_scan(int* __restrict__ cur){
    __shared__ int s[1024];
    int t = threadIdx.x;
    const int CH = 49;
    int base = t*CH;
    int m = NN - base; if (m > CH) m = CH; if (m < 0) m = 0;
    int sum = 0;
    for (int i = 0; i < m; ++i) sum += cur[base + i];
    s[t] = sum; __syncthreads();
    for (int off = 1; off < 1024; off <<= 1){
        int v = (t >= off) ? s[t - off] : 0; __syncthreads();
        s[t] += v; __syncthreads();
    }
    int run = s[t] - sum;
    for (int i = 0; i < m; ++i){
        int c = cur[base + i];
        cur[base + i] = run;
        run += c;
    }
}

// packed fill: ONE 8-byte store per edge (halves scattered-line traffic)
__global__ void k_fill(const int* __restrict__ ei, const float* __restrict__ ew,
                       int* __restrict__ cur, int2* __restrict__ csr){
    int e = blockIdx.x*256 + threadIdx.x;
    if (e >= NE) return;
    int src = ei[e], dst = ei[NE + e];
    int pos = atomicAdd(&cur[dst], 1);
    csr[pos] = make_int2(src, __float_as_int(ew[e]));
}

// ---------- one-time prep ----------

__global__ void k_pad(const float* __restrict__ x, float* __restrict__ h){
    int idx = blockIdx.x*256 + threadIdx.x;
    int n = idx >> 7, f = idx & 127;
    h[idx] = (f < FIN) ? x[n*FIN + f] : 0.f;
}

// fragWf[l] = bf16-frag( W_l @ w_ih^T )   [K=128][N=384]
__global__ void k_fuse(const float* __restrict__ W, const float* __restrict__ wih,
                       short* __restrict__ fwf){
    int idx = blockIdx.x*256 + threadIdx.x;   // 0..245759
    int l = idx / 49152;
    int r = idx % 49152;
    int k = r / 384, n = r % 384;
    const float* wl = W + l*16384 + k*128;
    const float* wi = wih + n*128;
    float acc = 0.f;
    for (int c = 0; c < 128; ++c) acc += wl[c]*wi[c];
    int lane = ((k>>3)&3)*16 + (n&15);
    fwf[l*49152 + (((n>>4)*4 + (k>>5))*64 + lane)*8 + (k&7)] = rne_bf16(acc);
}

__global__ void k_cvt_whh(const float* __restrict__ whh, short* __restrict__ fwhh){
    int idx = blockIdx.x*256 + threadIdx.x;   // 0..49151
    int k = idx / 384, n = idx % 384;
    float v = whh[n*128 + k];
    int lane = ((k>>3)&3)*16 + (n&15);
    fwhh[(((n>>4)*4 + (k>>5))*64 + lane)*8 + (k&7)] = rne_bf16(v);
}

__global__ void k_init_pool(unsigned* __restrict__ p){
    p[blockIdx.x*256 + threadIdx.x] = 0x007FFFFFu;
}

// ---------- per-layer ----------

// feature-sliced pull aggregation. slice = blockIdx.x & 7 -> XCD-local 3.2MB
// h-slice in L2. wave = one node; lane = (edge e4 = lane>>2) x (quad q = lane&3).
__global__ __launch_bounds__(256)
void k_agg(const float* __restrict__ h, const int* __restrict__ cur,
           const int2* __restrict__ csr, float* __restrict__ t){
    int slice = blockIdx.x & 7;
    int node  = (blockIdx.x >> 3)*4 + (threadIdx.x >> 6);
    int lane  = threadIdx.x & 63;
    int e4 = lane >> 2, q = lane & 3;
    int start = (node == 0) ? 0 : cur[node - 1];
    int end   = cur[node];
    const float* hs = h + slice*16 + q*4;
    float4 acc = {0.f, 0.f, 0.f, 0.f};
    for (int base = start; base < end; base += 16){
        int i = base + e4;
        if (i < end){
            int2 p = csr[i];
            float w = __int_as_float(p.y);
            const float4 v = *(const float4*)(hs + p.x*H);
            acc.x += w*v.x; acc.y += w*v.y; acc.z += w*v.z; acc.w += w*v.w;
        }
    }
    #pragma unroll
    for (int off = 4; off < 64; off <<= 1){
        acc.x += __shfl_xor(acc.x, off);
        acc.y += __shfl_xor(acc.y, off);
        acc.z += __shfl_xor(acc.z, off);
        acc.w += __shfl_xor(acc.w, off);
    }
    if (e4 == 0)
        *(float4*)(t + node*H + slice*16 + q*4) = acc;
}

// MFMA GRU: gi = t@Wf_l + b_ih ; gh = h@whh^T + b_hh ; h = GRU-update (in place)
__global__ __launch_bounds__(256)
void k_gruM(float* __restrict__ h, const float* __restrict__ t,
            const short* __restrict__ fwf, const short* __restrict__ fwhh,
            const float* __restrict__ b_ih, const float* __restrict__ b_hh){
    __shared__ float sg[16][772];
    int tid = threadIdx.x;
    int n0 = blockIdx.x * 16;
    int wave = tid >> 6, lane = tid & 63;
    int lane_lo = lane & 15, quad = lane >> 4;
    const float* A = (wave < 2) ? t : h;
    const short* B = (wave < 2) ? fwf : fwhh;
    int wv = (wave < 2) ? wave : wave - 2;
    int arow = n0 + lane_lo;

    f32x4 acc[12];
    #pragma unroll
    for (int i = 0; i < 12; ++i) acc[i] = (f32x4){0.f,0.f,0.f,0.f};

    #pragma unroll
    for (int kt = 0; kt < 4; ++kt){
        const float* ap = A + arow*H + kt*32 + quad*8;
        short8 af;
        #pragma unroll
        for (int j = 0; j < 8; ++j) af[j] = rne_bf16(ap[j]);
        const short* bp = B + (wv*48 + kt)*512 + lane*8;
        #pragma unroll
        for (int nt = 0; nt < 12; ++nt){
            short8 bf = *(const short8*)(bp + nt*2048);
            acc[nt] = __builtin_amdgcn_mfma_f32_16x16x32_bf16(af, bf, acc[nt], 0, 0, 0);
        }
    }

    int cwb = (wave < 2) ? wave*192 : 384 + (wave - 2)*192;
    #pragma unroll
    for (int nt = 0; nt < 12; ++nt){
        int col = cwb + nt*16 + lane_lo;
        #pragma unroll
        for (int r = 0; r < 4; ++r)
            sg[quad*4 + r][col] = acc[nt][r];
    }
    __syncthreads();

    int er = tid >> 4, j0 = (tid & 15) * 8;
    float* hp = h + (n0 + er)*H + j0;
    #pragma unroll
    for (int i = 0; i < 8; ++i){
        int j = j0 + i;
        float gir = sg[er][j]       + b_ih[j];
        float giz = sg[er][128 + j] + b_ih[128 + j];
        float gin = sg[er][256 + j] + b_ih[256 + j];
        float ghr = sg[er][384 + j] + b_hh[j];
        float ghz = sg[er][512 + j] + b_hh[128 + j];
        float ghn = sg[er][640 + j] + b_hh[256 + j];
        float rr = 1.f/(1.f + __expf(-(gir + ghr)));
        float zz = 1.f/(1.f + __expf(-(giz + ghz)));
        float nn = tanhf(gin + rr*ghn);
        float ho = hp[i];
        hp[i] = (1.f - zz)*nn + zz*ho;
    }
}

// ---------- tail ----------

__global__ void k_pool(const float* __restrict__ h, const int* __restrict__ batch,
                       unsigned* __restrict__ pooled){
    int idx = blockIdx.x*256 + threadIdx.x;
    int n = idx >> 7, f = idx & 127;
    int g = batch[n];
    unsigned u = __float_as_uint(h[idx]);
    u = (u & 0x80000000u) ? ~u : (u | 0x80000000u);
    atomicMax(pooled + g*H + f, u);
}

__global__ void k_head(const unsigned* __restrict__ pooled,
                       const float* __restrict__ d1w, const float* __restrict__ d1b,
                       const float* __restrict__ d2w, const float* __restrict__ d2b,
                       float* __restrict__ out){
    __shared__ float sp[128];
    __shared__ float shid[512];
    int g = blockIdx.x, tid = threadIdx.x;
    if (tid < 128){
        unsigned u = pooled[g*H + tid];
        sp[tid] = __uint_as_float((u & 0x80000000u) ? (u ^ 0x80000000u) : ~u);
    }
    __syncthreads();
    for (int o = tid; o < 512; o += 256){
        float acc = d1b[o];
        for (int k = 0; k < H; ++k) acc += sp[k] * d1w[o*H + k];
        shid[o] = fmaxf(acc, 0.f);
    }
    __syncthreads();
    if (tid < NC){
        float acc = d2b[tid];
        for (int o = 0; o < 512; ++o) acc += shid[o] * d2w[tid*512 + o];
        out[g*NC + tid] = acc;
    }
}

extern "C" void kernel_launch(void* const* d_in, const int* in_sizes, int n_in,
                              void* d_out, int out_size, void* d_ws, size_t ws_size,
                              hipStream_t stream){
    const float* x     = (const float*)d_in[0];
    const int*   ei    = (const int*)d_in[1];
    const int*   batch = (const int*)d_in[2];
    const float* ew    = (const float*)d_in[3];
    const float* W     = (const float*)d_in[4];
    const float* wih   = (const float*)d_in[5];
    const float* whh   = (const float*)d_in[6];
    const float* bih   = (const float*)d_in[7];
    const float* bhh   = (const float*)d_in[8];
    const float* d1w   = (const float*)d_in[9];
    const float* d1b   = (const float*)d_in[10];
    const float* d2w   = (const float*)d_in[11];
    const float* d2b   = (const float*)d_in[12];
    float* out = (float*)d_out;

    float* ws   = (float*)d_ws;
    float* h    = ws + OFF_H;
    float* t    = ws + OFF_T;
    int*   cur  = (int*)(ws + OFF_CUR);
    int2*  csr  = (int2*)(ws + OFF_CSR);
    unsigned* pooled = (unsigned*)(ws + OFF_POOL);
    short* fwf  = (short*)(ws + OFF_FWF);
    short* fwhh = (short*)(ws + OFF_FWHH);

    hipMemsetAsync(cur, 0, (size_t)NN*sizeof(int), stream);
    k_hist<<<6250, 256, 0, stream>>>(ei, cur);
    k_scan<<<1, 1024, 0, stream>>>(cur);
    k_fill<<<6250, 256, 0, stream>>>(ei, ew, cur, csr);

    k_fuse<<<960, 256, 0, stream>>>(W, wih, fwf);
    k_cvt_whh<<<192, 256, 0, stream>>>(whh, fwhh);
    k_pad<<<25000, 256, 0, stream>>>(x, h);
    k_init_pool<<<256, 256, 0, stream>>>(pooled);

    for (int l = 0; l < NL; ++l){
        k_agg<<<100000, 256, 0, stream>>>(h, cur, csr, t);
        k_gruM<<<3125, 256, 0, stream>>>(h, t, fwf + (size_t)l*49152, fwhh, bih, bhh);
    }

    k_pool<<<25000, 256, 0, stream>>>(h, batch, pooled);
    k_head<<<NG, 256, 0, stream>>>(pooled, d1w, d1b, d2w, d2b, out);
}

// Round 8
// 1266.010 us; speedup vs baseline: 1.4217x; 1.4217x over previous
//
#include <hip/hip_runtime.h>
#include <hip/hip_bf16.h>

#define NN 50000
#define NE 1600000
#define FIN 64
#define H 128
#define NL 5
#define NG 512
#define NC 10

typedef __attribute__((ext_vector_type(8))) short short8;
typedef __attribute__((ext_vector_type(4))) float f32x4;

// ws float-word offsets (total ~16.27M words = 65 MB)
#define OFF_H     0            // 6.4M floats
#define OFF_H2    6400000      // 6.4M ushorts = 3.2M words (bf16 shadow of h)
#define OFF_T     9600000      // 6.4M ushorts = 3.2M words (bf16 aggregate)
#define OFF_CUR   12800000     // 50016 ints
#define OFF_CSR   12850016     // 1.6M int2 = 3.2M words
#define OFF_POOL  16050016     // 65536 unsigned
#define OFF_FWF   16115552     // 245760 shorts (5 x 128x384 bf16 frag)
#define OFF_FWHH  16238432     // 49152 shorts

__device__ __forceinline__ short rne_bf16(float f){
    unsigned u = __float_as_uint(f);
    unsigned r = (u + 0x7FFFu + ((u >> 16) & 1u)) >> 16;
    return (short)r;
}
__device__ __forceinline__ float bf_lo(unsigned v){ return __uint_as_float(v << 16); }
__device__ __forceinline__ float bf_hi(unsigned v){ return __uint_as_float(v & 0xFFFF0000u); }

// ---------- CSR build ----------

__global__ void k_hist(const int* __restrict__ ei, int* __restrict__ cnt){
    int e = blockIdx.x*256 + threadIdx.x;
    if (e < NE) atomicAdd(&cnt[ei[NE + e]], 1);
}

__global__ void k_scan(int* __restrict__ cur){
    __shared__ int s[1024];
    int t = threadIdx.x;
    const int CH = 49;
    int base = t*CH;
    int m = NN - base; if (m > CH) m = CH; if (m < 0) m = 0;
    int sum = 0;
    for (int i = 0; i < m; ++i) sum += cur[base + i];
    s[t] = sum; __syncthreads();
    for (int off = 1; off < 1024; off <<= 1){
        int v = (t >= off) ? s[t - off] : 0; __syncthreads();
        s[t] += v; __syncthreads();
    }
    int run = s[t] - sum;
    for (int i = 0; i < m; ++i){
        int c = cur[base + i];
        cur[base + i] = run;
        run += c;
    }
}

__global__ void k_fill(const int* __restrict__ ei, const float* __restrict__ ew,
                       int* __restrict__ cur, int2* __restrict__ csr){
    int e = blockIdx.x*256 + threadIdx.x;
    if (e >= NE) return;
    int src = ei[e], dst = ei[NE + e];
    int pos = atomicAdd(&cur[dst], 1);
    csr[pos] = make_int2(src, __float_as_int(ew[e]));
}

// ---------- one-time prep ----------

__global__ void k_pad(const float* __restrict__ x, float* __restrict__ h,
                      ushort* __restrict__ h2){
    int idx = blockIdx.x*256 + threadIdx.x;
    int n = idx >> 7, f = idx & 127;
    float v = (f < FIN) ? x[n*FIN + f] : 0.f;
    h[idx] = v;
    h2[idx] = (ushort)rne_bf16(v);
}

// fragWf[l] = bf16-frag( W_l @ w_ih^T )   [K=128][N=384]
__global__ void k_fuse(const float* __restrict__ W, const float* __restrict__ wih,
                       short* __restrict__ fwf){
    int idx = blockIdx.x*256 + threadIdx.x;   // 0..245759
    int l = idx / 49152;
    int r = idx % 49152;
    int k = r / 384, n = r % 384;
    const float* wl = W + l*16384 + k*128;
    const float* wi = wih + n*128;
    float acc = 0.f;
    for (int c = 0; c < 128; ++c) acc += wl[c]*wi[c];
    int lane = ((k>>3)&3)*16 + (n&15);
    fwf[l*49152 + (((n>>4)*4 + (k>>5))*64 + lane)*8 + (k&7)] = rne_bf16(acc);
}

__global__ void k_cvt_whh(const float* __restrict__ whh, short* __restrict__ fwhh){
    int idx = blockIdx.x*256 + threadIdx.x;   // 0..49151
    int k = idx / 384, n = idx % 384;
    float v = whh[n*128 + k];
    int lane = ((k>>3)&3)*16 + (n&15);
    fwhh[(((n>>4)*4 + (k>>5))*64 + lane)*8 + (k&7)] = rne_bf16(v);
}

__global__ void k_init_pool(unsigned* __restrict__ p){
    p[blockIdx.x*256 + threadIdx.x] = 0x007FFFFFu;
}

// ---------- per-layer ----------

// pull aggregation from bf16 shadow: t[n] = bf16( sum ew * h2[src] )
// one wave per node; lane owns feature pair [2*lane, 2*lane+1] (one dword)
__global__ __launch_bounds__(256)
void k_agg(const ushort* __restrict__ h2, const int* __restrict__ cur,
           const int2* __restrict__ csr, ushort* __restrict__ t){
    int node = blockIdx.x*4 + (threadIdx.x >> 6);
    if (node >= NN) return;
    int lane = threadIdx.x & 63;
    int start = (node == 0) ? 0 : cur[node - 1];
    int end   = cur[node];
    float ax = 0.f, ay = 0.f;
    const ushort* hp = h2 + lane*2;
    for (int base = start; base < end; base += 64){
        int i = base + lane;
        int sv = 0; float wv = 0.f;
        if (i < end){ int2 p = csr[i]; sv = p.x; wv = __int_as_float(p.y); }
        int m = end - base; if (m > 64) m = 64;
        int j = 0;
        for (; j + 4 <= m; j += 4){
            int   s0 = __shfl(sv, j),   s1 = __shfl(sv, j+1);
            int   s2 = __shfl(sv, j+2), s3 = __shfl(sv, j+3);
            float w0 = __shfl(wv, j),   w1 = __shfl(wv, j+1);
            float w2 = __shfl(wv, j+2), w3 = __shfl(wv, j+3);
            unsigned v0 = *(const unsigned*)(hp + s0*H);
            unsigned v1 = *(const unsigned*)(hp + s1*H);
            unsigned v2 = *(const unsigned*)(hp + s2*H);
            unsigned v3 = *(const unsigned*)(hp + s3*H);
            ax += w0*bf_lo(v0); ay += w0*bf_hi(v0);
            ax += w1*bf_lo(v1); ay += w1*bf_hi(v1);
            ax += w2*bf_lo(v2); ay += w2*bf_hi(v2);
            ax += w3*bf_lo(v3); ay += w3*bf_hi(v3);
        }
        for (; j < m; ++j){
            int   s = __shfl(sv, j);
            float w = __shfl(wv, j);
            unsigned v = *(const unsigned*)(hp + s*H);
            ax += w*bf_lo(v); ay += w*bf_hi(v);
        }
    }
    unsigned pk = ((unsigned)(ushort)rne_bf16(ax)) | (((unsigned)(ushort)rne_bf16(ay)) << 16);
    *(unsigned*)(t + node*H + lane*2) = pk;
}

// MFMA GRU: gi = t@Wf_l + b_ih ; gh = h2@whh^T + b_hh ; h = GRU-update (in place)
__global__ __launch_bounds__(256)
void k_gruM(float* __restrict__ h, ushort* __restrict__ h2,
            const ushort* __restrict__ t,
            const short* __restrict__ fwf, const short* __restrict__ fwhh,
            const float* __restrict__ b_ih, const float* __restrict__ b_hh){
    __shared__ float sg[16][772];
    int tid = threadIdx.x;
    int n0 = blockIdx.x * 16;
    int wave = tid >> 6, lane = tid & 63;
    int lane_lo = lane & 15, quad = lane >> 4;
    const ushort* A = (wave < 2) ? t : h2;
    const short* B = (wave < 2) ? fwf : fwhh;
    int wv = (wave < 2) ? wave : wave - 2;
    int arow = n0 + lane_lo;

    f32x4 acc[12];
    #pragma unroll
    for (int i = 0; i < 12; ++i) acc[i] = (f32x4){0.f,0.f,0.f,0.f};

    #pragma unroll
    for (int kt = 0; kt < 4; ++kt){
        short8 af = *(const short8*)(A + arow*H + kt*32 + quad*8);
        const short* bp = B + (wv*48 + kt)*512 + lane*8;
        #pragma unroll
        for (int nt = 0; nt < 12; ++nt){
            short8 bf = *(const short8*)(bp + nt*2048);
            acc[nt] = __builtin_amdgcn_mfma_f32_16x16x32_bf16(af, bf, acc[nt], 0, 0, 0);
        }
    }

    int cwb = (wave < 2) ? wave*192 : 384 + (wave - 2)*192;
    #pragma unroll
    for (int nt = 0; nt < 12; ++nt){
        int col = cwb + nt*16 + lane_lo;
        #pragma unroll
        for (int r = 0; r < 4; ++r)
            sg[quad*4 + r][col] = acc[nt][r];
    }
    __syncthreads();

    int er = tid >> 4, j0 = (tid & 15) * 8;
    float* hp = h + (n0 + er)*H + j0;
    ushort* h2p = h2 + (n0 + er)*H + j0;
    short8 hb;
    #pragma unroll
    for (int i = 0; i < 8; ++i){
        int j = j0 + i;
        float gir = sg[er][j]       + b_ih[j];
        float giz = sg[er][128 + j] + b_ih[128 + j];
        float gin = sg[er][256 + j] + b_ih[256 + j];
        float ghr = sg[er][384 + j] + b_hh[j];
        float ghz = sg[er][512 + j] + b_hh[128 + j];
        float ghn = sg[er][640 + j] + b_hh[256 + j];
        float rr = 1.f/(1.f + __expf(-(gir + ghr)));
        float zz = 1.f/(1.f + __expf(-(giz + ghz)));
        float nn = tanhf(gin + rr*ghn);
        float ho = hp[i];
        float hv = (1.f - zz)*nn + zz*ho;
        hp[i] = hv;
        hb[i] = rne_bf16(hv);
    }
    *(short8*)h2p = hb;
}

// ---------- tail ----------

__global__ void k_pool(const float* __restrict__ h, const int* __restrict__ batch,
                       unsigned* __restrict__ pooled){
    int idx = blockIdx.x*256 + threadIdx.x;
    int n = idx >> 7, f = idx & 127;
    int g = batch[n];
    unsigned u = __float_as_uint(h[idx]);
    u = (u & 0x80000000u) ? ~u : (u | 0x80000000u);
    atomicMax(pooled + g*H + f, u);
}

__global__ void k_head(const unsigned* __restrict__ pooled,
                       const float* __restrict__ d1w, const float* __restrict__ d1b,
                       const float* __restrict__ d2w, const float* __restrict__ d2b,
                       float* __restrict__ out){
    __shared__ float sp[128];
    __shared__ float shid[512];
    int g = blockIdx.x, tid = threadIdx.x;
    if (tid < 128){
        unsigned u = pooled[g*H + tid];
        sp[tid] = __uint_as_float((u & 0x80000000u) ? (u ^ 0x80000000u) : ~u);
    }
    __syncthreads();
    for (int o = tid; o < 512; o += 256){
        float acc = d1b[o];
        for (int k = 0; k < H; ++k) acc += sp[k] * d1w[o*H + k];
        shid[o] = fmaxf(acc, 0.f);
    }
    __syncthreads();
    if (tid < NC){
        float acc = d2b[tid];
        for (int o = 0; o < 512; ++o) acc += shid[o] * d2w[tid*512 + o];
        out[g*NC + tid] = acc;
    }
}

extern "C" void kernel_launch(void* const* d_in, const int* in_sizes, int n_in,
                              void* d_out, int out_size, void* d_ws, size_t ws_size,
                              hipStream_t stream){
    const float* x     = (const float*)d_in[0];
    const int*   ei    = (const int*)d_in[1];
    const int*   batch = (const int*)d_in[2];
    const float* ew    = (const float*)d_in[3];
    const float* W     = (const float*)d_in[4];
    const float* wih   = (const float*)d_in[5];
    const float* whh   = (const float*)d_in[6];
    const float* bih   = (const float*)d_in[7];
    const float* bhh   = (const float*)d_in[8];
    const float* d1w   = (const float*)d_in[9];
    const float* d1b   = (const float*)d_in[10];
    const float* d2w   = (const float*)d_in[11];
    const float* d2b   = (const float*)d_in[12];
    float* out = (float*)d_out;

    float*  ws  = (float*)d_ws;
    float*  h   = ws + OFF_H;
    ushort* h2  = (ushort*)(ws + OFF_H2);
    ushort* t   = (ushort*)(ws + OFF_T);
    int*    cur = (int*)(ws + OFF_CUR);
    int2*   csr = (int2*)(ws + OFF_CSR);
    unsigned* pooled = (unsigned*)(ws + OFF_POOL);
    short*  fwf  = (short*)(ws + OFF_FWF);
    short*  fwhh = (short*)(ws + OFF_FWHH);

    hipMemsetAsync(cur, 0, (size_t)NN*sizeof(int), stream);
    k_hist<<<6250, 256, 0, stream>>>(ei, cur);
    k_scan<<<1, 1024, 0, stream>>>(cur);
    k_fill<<<6250, 256, 0, stream>>>(ei, ew, cur, csr);

    k_fuse<<<960, 256, 0, stream>>>(W, wih, fwf);
    k_cvt_whh<<<192, 256, 0, stream>>>(whh, fwhh);
    k_pad<<<25000, 256, 0, stream>>>(x, h, h2);
    k_init_pool<<<256, 256, 0, stream>>>(pooled);

    for (int l = 0; l < NL; ++l){
        k_agg<<<12500, 256, 0, stream>>>(h2, cur, csr, t);
        k_gruM<<<3125, 256, 0, stream>>>(h, h2, t, fwf + (size_t)l*49152, fwhh, bih, bhh);
    }

    k_pool<<<25000, 256, 0, stream>>>(h, batch, pooled);
    k_head<<<NG, 256, 0, stream>>>(pooled, d1w, d1b, d2w, d2b, out);
}

// Round 10
// 996.569 us; speedup vs baseline: 1.8061x; 1.2704x over previous
//
#include <hip/hip_runtime.h>
#include <hip/hip_bf16.h>

#define NN 50000
#define NE 1600000
#define FIN 64
#define H 128
#define NL 5
#define NG 512
#define NC 10

typedef __attribute__((ext_vector_type(8))) short short8;
typedef __attribute__((ext_vector_type(4))) float f32x4;

// ws float-word offsets (~16.27M words = 65 MB)
#define OFF_H     0            // 6.4M floats
#define OFF_H2A   6400000      // 6.4M ushorts = 3.2M words (bf16 h, ping)
#define OFF_H2B   9600000      // 6.4M ushorts = 3.2M words (bf16 h, pong)
#define OFF_CUR   12800000     // 50016 ints
#define OFF_CSR   12850016     // 1.6M int2 = 3.2M words
#define OFF_POOL  16050016     // 65536 unsigned
#define OFF_FWF   16115552     // 245760 shorts (5 x 128x384 bf16 frag)
#define OFF_FWHH  16238432     // 49152 shorts

__device__ __forceinline__ short rne_bf16(float f){
    unsigned u = __float_as_uint(f);
    unsigned r = (u + 0x7FFFu + ((u >> 16) & 1u)) >> 16;
    return (short)r;
}
__device__ __forceinline__ float bf_lo(unsigned v){ return __uint_as_float(v << 16); }
__device__ __forceinline__ float bf_hi(unsigned v){ return __uint_as_float(v & 0xFFFF0000u); }

// ---------- CSR build ----------

__global__ void k_hist(const int* __restrict__ ei, int* __restrict__ cnt){
    int e = blockIdx.x*256 + threadIdx.x;
    if (e < NE) atomicAdd(&cnt[ei[NE + e]], 1);
}

__global__ void k_scan(int* __restrict__ cur){
    __shared__ int s[1024];
    int t = threadIdx.x;
    const int CH = 49;
    int base = t*CH;
    int m = NN - base; if (m > CH) m = CH; if (m < 0) m = 0;
    int sum = 0;
    for (int i = 0; i < m; ++i) sum += cur[base + i];
    s[t] = sum; __syncthreads();
    for (int off = 1; off < 1024; off <<= 1){
        int v = (t >= off) ? s[t - off] : 0; __syncthreads();
        s[t] += v; __syncthreads();
    }
    int run = s[t] - sum;
    for (int i = 0; i < m; ++i){
        int c = cur[base + i];
        cur[base + i] = run;
        run += c;
    }
}

__global__ void k_fill(const int* __restrict__ ei, const float* __restrict__ ew,
                       int* __restrict__ cur, int2* __restrict__ csr){
    int e = blockIdx.x*256 + threadIdx.x;
    if (e >= NE) return;
    int src = ei[e], dst = ei[NE + e];
    int pos = atomicAdd(&cur[dst], 1);
    csr[pos] = make_int2(src, __float_as_int(ew[e]));
}

// ---------- one-time prep ----------

__global__ void k_pad(const float* __restrict__ x, float* __restrict__ h,
                      ushort* __restrict__ h2a){
    int idx = blockIdx.x*256 + threadIdx.x;
    int n = idx >> 7, f = idx & 127;
    float v = (f < FIN) ? x[n*FIN + f] : 0.f;
    h[idx] = v;
    h2a[idx] = (ushort)rne_bf16(v);
}

// fragWf[l] = bf16-frag( W_l @ w_ih^T )   [K=128][N=384]
__global__ void k_fuse(const float* __restrict__ W, const float* __restrict__ wih,
                       short* __restrict__ fwf){
    int idx = blockIdx.x*256 + threadIdx.x;   // 0..245759
    int l = idx / 49152;
    int r = idx % 49152;
    int k = r / 384, n = r % 384;
    const float* wl = W + l*16384 + k*128;
    const float* wi = wih + n*128;
    float acc = 0.f;
    for (int c = 0; c < 128; ++c) acc += wl[c]*wi[c];
    int lane = ((k>>3)&3)*16 + (n&15);
    fwf[l*49152 + (((n>>4)*4 + (k>>5))*64 + lane)*8 + (k&7)] = rne_bf16(acc);
}

__global__ void k_cvt_whh(const float* __restrict__ whh, short* __restrict__ fwhh){
    int idx = blockIdx.x*256 + threadIdx.x;   // 0..49151
    int k = idx / 384, n = idx % 384;
    float v = whh[n*128 + k];
    int lane = ((k>>3)&3)*16 + (n&15);
    fwhh[(((n>>4)*4 + (k>>5))*64 + lane)*8 + (k&7)] = rne_bf16(v);
}

__global__ void k_init_pool(unsigned* __restrict__ p){
    p[blockIdx.x*256 + threadIdx.x] = 0x007FFFFFu;
}

// ---------- fused layer: aggregate -> dual MFMA GEMM -> register GRU ----------
// Ping-pong: ALL bf16 reads hit h2r (never written this launch); writes go to
// h2w. No cross-block or intra-block h2 races. fp32 h is owner-lane-only.
__global__ __launch_bounds__(256)
void k_layer(float* __restrict__ h, const ushort* __restrict__ h2r,
             ushort* __restrict__ h2w,
             const int* __restrict__ cur, const int2* __restrict__ csr,
             const short* __restrict__ fwf, const short* __restrict__ fwhh,
             const float* __restrict__ b_ih, const float* __restrict__ b_hh){
    __shared__ ushort tl[16*136];             // row stride 136 ushorts (16B-aligned)
    int tid = threadIdx.x;
    int n0 = blockIdx.x * 16;
    int wave = tid >> 6, lane = tid & 63;
    int lane_lo = lane & 15, quad = lane >> 4;

    // ---- phase 1: pull-aggregate 4 nodes per wave into LDS (bf16) ----
    unsigned* tld = (unsigned*)tl;
    for (int sub = 0; sub < 4; ++sub){
        int node = n0 + wave*4 + sub;
        int start = (node == 0) ? 0 : cur[node - 1];
        int end   = cur[node];
        float ax = 0.f, ay = 0.f;
        const ushort* hp = h2r + lane*2;
        for (int base = start; base < end; base += 64){
            int i = base + lane;
            int sv = 0; float wv = 0.f;
            if (i < end){ int2 p = csr[i]; sv = p.x; wv = __int_as_float(p.y); }
            int m = end - base; if (m > 64) m = 64;
            int j = 0;
            for (; j + 4 <= m; j += 4){
                int   s0 = __shfl(sv, j),   s1 = __shfl(sv, j+1);
                int   s2 = __shfl(sv, j+2), s3 = __shfl(sv, j+3);
                float w0 = __shfl(wv, j),   w1 = __shfl(wv, j+1);
                float w2 = __shfl(wv, j+2), w3 = __shfl(wv, j+3);
                unsigned v0 = *(const unsigned*)(hp + s0*H);
                unsigned v1 = *(const unsigned*)(hp + s1*H);
                unsigned v2 = *(const unsigned*)(hp + s2*H);
                unsigned v3 = *(const unsigned*)(hp + s3*H);
                ax += w0*bf_lo(v0); ay += w0*bf_hi(v0);
                ax += w1*bf_lo(v1); ay += w1*bf_hi(v1);
                ax += w2*bf_lo(v2); ay += w2*bf_hi(v2);
                ax += w3*bf_lo(v3); ay += w3*bf_hi(v3);
            }
            for (; j < m; ++j){
                int   s = __shfl(sv, j);
                float w = __shfl(wv, j);
                unsigned v = *(const unsigned*)(hp + s*H);
                ax += w*bf_lo(v); ay += w*bf_hi(v);
            }
        }
        tld[(wave*4 + sub)*68 + lane] =
            ((unsigned)(ushort)rne_bf16(ax)) | (((unsigned)(ushort)rne_bf16(ay)) << 16);
    }
    __syncthreads();

    // ---- phase 2: dual GEMM; wave w owns cols w*32+{0..31} of each section ----
    f32x4 ai[6], ah[6];                       // [s*2 + t16]
    #pragma unroll
    for (int i = 0; i < 6; ++i){ ai[i] = (f32x4){0.f,0.f,0.f,0.f}; ah[i] = (f32x4){0.f,0.f,0.f,0.f}; }

    const ushort* arow_t = tl + lane_lo*136;
    const ushort* arow_h = h2r + (size_t)(n0 + lane_lo)*H;
    #pragma unroll
    for (int kt = 0; kt < 4; ++kt){
        short8 at  = *(const short8*)(arow_t + kt*32 + quad*8);
        short8 ahh = *(const short8*)(arow_h + kt*32 + quad*8);
        #pragma unroll
        for (int s = 0; s < 3; ++s){
            #pragma unroll
            for (int t16 = 0; t16 < 2; ++t16){
                int tile = (s*8 + wave*2 + t16)*4 + kt;
                short8 bi = *(const short8*)(fwf  + tile*512 + lane*8);
                short8 bh = *(const short8*)(fwhh + tile*512 + lane*8);
                ai[s*2+t16] = __builtin_amdgcn_mfma_f32_16x16x32_bf16(at,  bi, ai[s*2+t16], 0, 0, 0);
                ah[s*2+t16] = __builtin_amdgcn_mfma_f32_16x16x32_bf16(ahh, bh, ah[s*2+t16], 0, 0, 0);
            }
        }
    }

    // ---- phase 3: register-resident GRU update ----
    #pragma unroll
    for (int t16 = 0; t16 < 2; ++t16){
        int j = wave*32 + t16*16 + lane_lo;
        float bir = b_ih[j], biz = b_ih[128 + j], bin_ = b_ih[256 + j];
        float bhr = b_hh[j], bhz = b_hh[128 + j], bhn  = b_hh[256 + j];
        #pragma unroll
        for (int r = 0; r < 4; ++r){
            int row = n0 + quad*4 + r;
            float gir = ai[t16][r]     + bir, ghr = ah[t16][r]     + bhr;
            float giz = ai[2 + t16][r] + biz, ghz = ah[2 + t16][r] + bhz;
            float gin = ai[4 + t16][r] + bin_, ghn = ah[4 + t16][r] + bhn;
            float rr = 1.f/(1.f + __expf(-(gir + ghr)));
            float zz = 1.f/(1.f + __expf(-(giz + ghz)));
            float nn = tanhf(gin + rr*ghn);
            float ho = h[(size_t)row*H + j];
            float hv = (1.f - zz)*nn + zz*ho;
            h[(size_t)row*H + j] = hv;
            h2w[(size_t)row*H + j] = (ushort)rne_bf16(hv);
        }
    }
}

// ---------- tail ----------

__global__ void k_pool(const float* __restrict__ h, const int* __restrict__ batch,
                       unsigned* __restrict__ pooled){
    int idx = blockIdx.x*256 + threadIdx.x;
    int n = idx >> 7, f = idx & 127;
    int g = batch[n];
    unsigned u = __float_as_uint(h[idx]);
    u = (u & 0x80000000u) ? ~u : (u | 0x80000000u);
    atomicMax(pooled + g*H + f, u);
}

__global__ void k_head(const unsigned* __restrict__ pooled,
                       const float* __restrict__ d1w, const float* __restrict__ d1b,
                       const float* __restrict__ d2w, const float* __restrict__ d2b,
                       float* __restrict__ out){
    __shared__ float sp[128];
    __shared__ float shid[512];
    int g = blockIdx.x, tid = threadIdx.x;
    if (tid < 128){
        unsigned u = pooled[g*H + tid];
        sp[tid] = __uint_as_float((u & 0x80000000u) ? (u ^ 0x80000000u) : ~u);
    }
    __syncthreads();
    for (int o = tid; o < 512; o += 256){
        float acc = d1b[o];
        for (int k = 0; k < H; ++k) acc += sp[k] * d1w[o*H + k];
        shid[o] = fmaxf(acc, 0.f);
    }
    __syncthreads();
    if (tid < NC){
        float acc = d2b[tid];
        for (int o = 0; o < 512; ++o) acc += shid[o] * d2w[tid*512 + o];
        out[g*NC + tid] = acc;
    }
}

extern "C" void kernel_launch(void* const* d_in, const int* in_sizes, int n_in,
                              void* d_out, int out_size, void* d_ws, size_t ws_size,
                              hipStream_t stream){
    const float* x     = (const float*)d_in[0];
    const int*   ei    = (const int*)d_in[1];
    const int*   batch = (const int*)d_in[2];
    const float* ew    = (const float*)d_in[3];
    const float* W     = (const float*)d_in[4];
    const float* wih   = (const float*)d_in[5];
    const float* whh   = (const float*)d_in[6];
    const float* bih   = (const float*)d_in[7];
    const float* bhh   = (const float*)d_in[8];
    const float* d1w   = (const float*)d_in[9];
    const float* d1b   = (const float*)d_in[10];
    const float* d2w   = (const float*)d_in[11];
    const float* d2b   = (const float*)d_in[12];
    float* out = (float*)d_out;

    float*  ws  = (float*)d_ws;
    float*  h   = ws + OFF_H;
    ushort* h2a = (ushort*)(ws + OFF_H2A);
    ushort* h2b = (ushort*)(ws + OFF_H2B);
    int*    cur = (int*)(ws + OFF_CUR);
    int2*   csr = (int2*)(ws + OFF_CSR);
    unsigned* pooled = (unsigned*)(ws + OFF_POOL);
    short*  fwf  = (short*)(ws + OFF_FWF);
    short*  fwhh = (short*)(ws + OFF_FWHH);

    hipMemsetAsync(cur, 0, (size_t)NN*sizeof(int), stream);
    k_hist<<<6250, 256, 0, stream>>>(ei, cur);
    k_scan<<<1, 1024, 0, stream>>>(cur);
    k_fill<<<6250, 256, 0, stream>>>(ei, ew, cur, csr);

    k_fuse<<<960, 256, 0, stream>>>(W, wih, fwf);
    k_cvt_whh<<<192, 256, 0, stream>>>(whh, fwhh);
    k_pad<<<25000, 256, 0, stream>>>(x, h, h2a);
    k_init_pool<<<256, 256, 0, stream>>>(pooled);

    for (int l = 0; l < NL; ++l){
        ushort* h2r = (l & 1) ? h2b : h2a;
        ushort* h2w = (l & 1) ? h2a : h2b;
        k_layer<<<3125, 256, 0, stream>>>(h, h2r, h2w, cur, csr,
                                          fwf + (size_t)l*49152, fwhh, bih, bhh);
    }

    k_pool<<<25000, 256, 0, stream>>>(h, batch, pooled);
    k_head<<<NG, 256, 0, stream>>>(pooled, d1w, d1b, d2w, d2b, out);
}

// Round 11
// 975.198 us; speedup vs baseline: 1.8457x; 1.0219x over previous
//
#include <hip/hip_runtime.h>
#include <hip/hip_bf16.h>

#define NN 50000
#define NE 1600000
#define FIN 64
#define H 128
#define NL 5
#define NG 512
#define NC 10

typedef __attribute__((ext_vector_type(8))) short short8;
typedef __attribute__((ext_vector_type(4))) float f32x4;

// ws float-word offsets (~65 MB)
#define OFF_H     0            // 6.4M floats
#define OFF_H2A   6400000      // bf16 h ping (3.2M words)
#define OFF_H2B   9600000      // bf16 h pong (3.2M words)
#define OFF_CUR   12800000     // 50016 ints
#define OFF_CSR   12850016     // 1.6M packed words (ushort src | bf16 w << 16)
#define OFF_POOL  16050016     // 65536 unsigned
#define OFF_FWF   16115552     // 245760 shorts (5 x 128x384 bf16 frag)
#define OFF_FWHH  16238432     // 49152 shorts

__device__ __forceinline__ short rne_bf16(float f){
    unsigned u = __float_as_uint(f);
    unsigned r = (u + 0x7FFFu + ((u >> 16) & 1u)) >> 16;
    return (short)r;
}
__device__ __forceinline__ float bf_lo(unsigned v){ return __uint_as_float(v << 16); }
__device__ __forceinline__ float bf_hi(unsigned v){ return __uint_as_float(v & 0xFFFF0000u); }

// ---------- CSR build ----------

__global__ void k_hist(const int* __restrict__ ei, int* __restrict__ cnt){
    int e = blockIdx.x*256 + threadIdx.x;
    if (e < NE) atomicAdd(&cnt[ei[NE + e]], 1);
}

__global__ void k_scan(int* __restrict__ cur){
    __shared__ int s[1024];
    int t = threadIdx.x;
    const int CH = 49;
    int base = t*CH;
    int m = NN - base; if (m > CH) m = CH; if (m < 0) m = 0;
    int sum = 0;
    for (int i = 0; i < m; ++i) sum += cur[base + i];
    s[t] = sum; __syncthreads();
    for (int off = 1; off < 1024; off <<= 1){
        int v = (t >= off) ? s[t - off] : 0; __syncthreads();
        s[t] += v; __syncthreads();
    }
    int run = s[t] - sum;
    for (int i = 0; i < m; ++i){
        int c = cur[base + i];
        cur[base + i] = run;
        run += c;
    }
}

// packed fill: ONE 4-byte store per edge (src in low 16, bf16 weight in high 16)
__global__ void k_fill(const int* __restrict__ ei, const float* __restrict__ ew,
                       int* __restrict__ cur, unsigned* __restrict__ csr){
    int e = blockIdx.x*256 + threadIdx.x;
    if (e >= NE) return;
    int src = ei[e], dst = ei[NE + e];
    int pos = atomicAdd(&cur[dst], 1);
    csr[pos] = (unsigned)src | (((unsigned)(ushort)rne_bf16(ew[e])) << 16);
}

// ---------- one-time prep ----------

__global__ void k_pad(const float* __restrict__ x, float* __restrict__ h,
                      ushort* __restrict__ h2a){
    int idx = blockIdx.x*256 + threadIdx.x;
    int n = idx >> 7, f = idx & 127;
    float v = (f < FIN) ? x[n*FIN + f] : 0.f;
    h[idx] = v;
    h2a[idx] = (ushort)rne_bf16(v);
}

// fragWf[l] = bf16-frag( W_l @ w_ih^T )   [K=128][N=384]
__global__ void k_fuse(const float* __restrict__ W, const float* __restrict__ wih,
                       short* __restrict__ fwf){
    int idx = blockIdx.x*256 + threadIdx.x;   // 0..245759
    int l = idx / 49152;
    int r = idx % 49152;
    int k = r / 384, n = r % 384;
    const float* wl = W + l*16384 + k*128;
    const float* wi = wih + n*128;
    float acc = 0.f;
    for (int c = 0; c < 128; ++c) acc += wl[c]*wi[c];
    int lane = ((k>>3)&3)*16 + (n&15);
    fwf[l*49152 + (((n>>4)*4 + (k>>5))*64 + lane)*8 + (k&7)] = rne_bf16(acc);
}

__global__ void k_cvt_whh(const float* __restrict__ whh, short* __restrict__ fwhh){
    int idx = blockIdx.x*256 + threadIdx.x;   // 0..49151
    int k = idx / 384, n = idx % 384;
    float v = whh[n*128 + k];
    int lane = ((k>>3)&3)*16 + (n&15);
    fwhh[(((n>>4)*4 + (k>>5))*64 + lane)*8 + (k&7)] = rne_bf16(v);
}

__global__ void k_init_pool(unsigned* __restrict__ p){
    p[blockIdx.x*256 + threadIdx.x] = 0x007FFFFFu;   // enc(-inf)
}

// ---------- fused layer: aggregate -> dual MFMA GEMM -> register GRU ----------
// Ping-pong: all bf16 reads hit h2r; writes go h2w. last=1: fold segment-max
// pooling into the epilogue and skip dead h/h2w writes.
__global__ __launch_bounds__(256)
void k_layer(float* __restrict__ h, const ushort* __restrict__ h2r,
             ushort* __restrict__ h2w,
             const int* __restrict__ cur, const unsigned* __restrict__ csr,
             const short* __restrict__ fwf, const short* __restrict__ fwhh,
             const float* __restrict__ b_ih, const float* __restrict__ b_hh,
             const int* __restrict__ batch, unsigned* __restrict__ pooled,
             int last){
    __shared__ ushort tl[16*136];             // row stride 136 ushorts (16B-aligned)
    int tid = threadIdx.x;
    int n0 = blockIdx.x * 16;
    int wave = tid >> 6, lane = tid & 63;
    int lane_lo = lane & 15, quad = lane >> 4;

    // ---- phase 1: pull-aggregate 4 nodes per wave into LDS (bf16) ----
    unsigned* tld = (unsigned*)tl;
    for (int sub = 0; sub < 4; ++sub){
        int node = n0 + wave*4 + sub;
        int start = (node == 0) ? 0 : cur[node - 1];
        int end   = cur[node];
        float ax = 0.f, ay = 0.f;
        const ushort* hp = h2r + lane*2;
        for (int base = start; base < end; base += 64){
            int i = base + lane;
            unsigned pkv = (i < end) ? csr[i] : 0;
            int m = end - base; if (m > 64) m = 64;
            int j = 0;
            for (; j + 8 <= m; j += 8){
                unsigned e0 = __shfl(pkv, j+0), e1 = __shfl(pkv, j+1);
                unsigned e2 = __shfl(pkv, j+2), e3 = __shfl(pkv, j+3);
                unsigned e4 = __shfl(pkv, j+4), e5 = __shfl(pkv, j+5);
                unsigned e6 = __shfl(pkv, j+6), e7 = __shfl(pkv, j+7);
                unsigned v0 = *(const unsigned*)(hp + (e0 & 0xFFFFu)*H);
                unsigned v1 = *(const unsigned*)(hp + (e1 & 0xFFFFu)*H);
                unsigned v2 = *(const unsigned*)(hp + (e2 & 0xFFFFu)*H);
                unsigned v3 = *(const unsigned*)(hp + (e3 & 0xFFFFu)*H);
                unsigned v4 = *(const unsigned*)(hp + (e4 & 0xFFFFu)*H);
                unsigned v5 = *(const unsigned*)(hp + (e5 & 0xFFFFu)*H);
                unsigned v6 = *(const unsigned*)(hp + (e6 & 0xFFFFu)*H);
                unsigned v7 = *(const unsigned*)(hp + (e7 & 0xFFFFu)*H);
                ax += bf_hi(e0)*bf_lo(v0); ay += bf_hi(e0)*bf_hi(v0);
                ax += bf_hi(e1)*bf_lo(v1); ay += bf_hi(e1)*bf_hi(v1);
                ax += bf_hi(e2)*bf_lo(v2); ay += bf_hi(e2)*bf_hi(v2);
                ax += bf_hi(e3)*bf_lo(v3); ay += bf_hi(e3)*bf_hi(v3);
                ax += bf_hi(e4)*bf_lo(v4); ay += bf_hi(e4)*bf_hi(v4);
                ax += bf_hi(e5)*bf_lo(v5); ay += bf_hi(e5)*bf_hi(v5);
                ax += bf_hi(e6)*bf_lo(v6); ay += bf_hi(e6)*bf_hi(v6);
                ax += bf_hi(e7)*bf_lo(v7); ay += bf_hi(e7)*bf_hi(v7);
            }
            for (; j < m; ++j){
                unsigned e = __shfl(pkv, j);
                unsigned v = *(const unsigned*)(hp + (e & 0xFFFFu)*H);
                ax += bf_hi(e)*bf_lo(v); ay += bf_hi(e)*bf_hi(v);
            }
        }
        tld[(wave*4 + sub)*68 + lane] =
            ((unsigned)(ushort)rne_bf16(ax)) | (((unsigned)(ushort)rne_bf16(ay)) << 16);
    }
    __syncthreads();

    // ---- phase 2: dual GEMM; wave w owns cols w*32+{0..31} of each section ----
    f32x4 ai[6], ah[6];                       // [s*2 + t16]
    #pragma unroll
    for (int i = 0; i < 6; ++i){ ai[i] = (f32x4){0.f,0.f,0.f,0.f}; ah[i] = (f32x4){0.f,0.f,0.f,0.f}; }

    const ushort* arow_t = tl + lane_lo*136;
    const ushort* arow_h = h2r + (size_t)(n0 + lane_lo)*H;
    #pragma unroll
    for (int kt = 0; kt < 4; ++kt){
        short8 at  = *(const short8*)(arow_t + kt*32 + quad*8);
        short8 ahh = *(const short8*)(arow_h + kt*32 + quad*8);
        #pragma unroll
        for (int s = 0; s < 3; ++s){
            #pragma unroll
            for (int t16 = 0; t16 < 2; ++t16){
                int tile = (s*8 + wave*2 + t16)*4 + kt;
                short8 bi = *(const short8*)(fwf  + tile*512 + lane*8);
                short8 bh = *(const short8*)(fwhh + tile*512 + lane*8);
                ai[s*2+t16] = __builtin_amdgcn_mfma_f32_16x16x32_bf16(at,  bi, ai[s*2+t16], 0, 0, 0);
                ah[s*2+t16] = __builtin_amdgcn_mfma_f32_16x16x32_bf16(ahh, bh, ah[s*2+t16], 0, 0, 0);
            }
        }
    }

    // ---- phase 3: register-resident GRU update (+ fused pool on last) ----
    #pragma unroll
    for (int t16 = 0; t16 < 2; ++t16){
        int j = wave*32 + t16*16 + lane_lo;
        float bir = b_ih[j], biz = b_ih[128 + j], bin_ = b_ih[256 + j];
        float bhr = b_hh[j], bhz = b_hh[128 + j], bhn  = b_hh[256 + j];
        #pragma unroll
        for (int r = 0; r < 4; ++r){
            int row = n0 + quad*4 + r;
            float gir = ai[t16][r]     + bir, ghr = ah[t16][r]     + bhr;
            float giz = ai[2 + t16][r] + biz, ghz = ah[2 + t16][r] + bhz;
            float gin = ai[4 + t16][r] + bin_, ghn = ah[4 + t16][r] + bhn;
            float rr = 1.f/(1.f + __expf(-(gir + ghr)));
            float zz = 1.f/(1.f + __expf(-(giz + ghz)));
            float nn = tanhf(gin + rr*ghn);
            float ho = h[(size_t)row*H + j];
            float hv = (1.f - zz)*nn + zz*ho;
            if (!last){
                h[(size_t)row*H + j] = hv;
                h2w[(size_t)row*H + j] = (ushort)rne_bf16(hv);
            } else {
                int g = batch[row];
                unsigned u = __float_as_uint(hv);
                u = (u & 0x80000000u) ? ~u : (u | 0x80000000u);
                atomicMax(pooled + g*H + j, u);
            }
        }
    }
}

// ---------- tail ----------

__global__ void k_head(const unsigned* __restrict__ pooled,
                       const float* __restrict__ d1w, const float* __restrict__ d1b,
                       const float* __restrict__ d2w, const float* __restrict__ d2b,
                       float* __restrict__ out){
    __shared__ float sp[128];
    __shared__ float shid[512];
    int g = blockIdx.x, tid = threadIdx.x;
    if (tid < 128){
        unsigned u = pooled[g*H + tid];
        sp[tid] = __uint_as_float((u & 0x80000000u) ? (u ^ 0x80000000u) : ~u);
    }
    __syncthreads();
    for (int o = tid; o < 512; o += 256){
        float acc = d1b[o];
        for (int k = 0; k < H; ++k) acc += sp[k] * d1w[o*H + k];
        shid[o] = fmaxf(acc, 0.f);
    }
    __syncthreads();
    if (tid < NC){
        float acc = d2b[tid];
        for (int o = 0; o < 512; ++o) acc += shid[o] * d2w[tid*512 + o];
        out[g*NC + tid] = acc;
    }
}

extern "C" void kernel_launch(void* const* d_in, const int* in_sizes, int n_in,
                              void* d_out, int out_size, void* d_ws, size_t ws_size,
                              hipStream_t stream){
    const float* x     = (const float*)d_in[0];
    const int*   ei    = (const int*)d_in[1];
    const int*   batch = (const int*)d_in[2];
    const float* ew    = (const float*)d_in[3];
    const float* W     = (const float*)d_in[4];
    const float* wih   = (const float*)d_in[5];
    const float* whh   = (const float*)d_in[6];
    const float* bih   = (const float*)d_in[7];
    const float* bhh   = (const float*)d_in[8];
    const float* d1w   = (const float*)d_in[9];
    const float* d1b   = (const float*)d_in[10];
    const float* d2w   = (const float*)d_in[11];
    const float* d2b   = (const float*)d_in[12];
    float* out = (float*)d_out;

    float*  ws  = (float*)d_ws;
    float*  h   = ws + OFF_H;
    ushort* h2a = (ushort*)(ws + OFF_H2A);
    ushort* h2b = (ushort*)(ws + OFF_H2B);
    int*    cur = (int*)(ws + OFF_CUR);
    unsigned* csr = (unsigned*)(ws + OFF_CSR);
    unsigned* pooled = (unsigned*)(ws + OFF_POOL);
    short*  fwf  = (short*)(ws + OFF_FWF);
    short*  fwhh = (short*)(ws + OFF_FWHH);

    hipMemsetAsync(cur, 0, (size_t)NN*sizeof(int), stream);
    k_hist<<<6250, 256, 0, stream>>>(ei, cur);
    k_scan<<<1, 1024, 0, stream>>>(cur);
    k_fill<<<6250, 256, 0, stream>>>(ei, ew, cur, csr);

    k_fuse<<<960, 256, 0, stream>>>(W, wih, fwf);
    k_cvt_whh<<<192, 256, 0, stream>>>(whh, fwhh);
    k_pad<<<25000, 256, 0, stream>>>(x, h, h2a);
    k_init_pool<<<256, 256, 0, stream>>>(pooled);

    for (int l = 0; l < NL; ++l){
        ushort* h2r = (l & 1) ? h2b : h2a;
        ushort* h2w = (l & 1) ? h2a : h2b;
        k_layer<<<3125, 256, 0, stream>>>(h, h2r, h2w, cur, csr,
                                          fwf + (size_t)l*49152, fwhh, bih, bhh,
                                          batch, pooled, (l == NL-1) ? 1 : 0);
    }

    k_head<<<NG, 256, 0, stream>>>(pooled, d1w, d1b, d2w, d2b, out);
}